// Round 4
// baseline (584.219 us; speedup 1.0000x reference)
//
#include <hip/hip_runtime.h>
#include <hip/hip_bf16.h>

#define N_NODES 50000
#define N_EDGES 800000
#define NC 16
#define FDIM 13
#define HID 32
#define RT_ROW 528   // 16 outputs * 32 hidden + 16 b2-terms (bf16)
#define EPB 64       // edges per block in k_msg

typedef unsigned short ushort_t;
typedef unsigned int uint_t;
typedef __attribute__((ext_vector_type(8))) unsigned short u16x8;

__device__ __forceinline__ float bf2f(ushort_t u) {
  union { unsigned int i; float f; } v; v.i = ((unsigned int)u) << 16; return v.f;
}
__device__ __forceinline__ ushort_t f2bf(float f) {
  union { unsigned int i; float f; } v; v.f = f;
  unsigned int r = v.i + 0x7FFFu + ((v.i >> 16) & 1u);   // RNE
  return (ushort_t)(r >> 16);
}
__device__ __forceinline__ float loadf(const void* p, int i, int isf32) {
  return isf32 ? ((const float*)p)[i] : bf2f(((const ushort_t*)p)[i]);
}
__device__ __forceinline__ float sigmoidf_(float x) { return 1.0f / (1.0f + __expf(-x)); }
__device__ __forceinline__ float tanhf_(float x) { return 1.0f - 2.0f / (__expf(2.0f * x) + 1.0f); }

// ---- dtype detector (1 = fp32 inputs) ----
__global__ void k_detect(const unsigned int* __restrict__ w, int* __restrict__ flag) {
  __shared__ int cnt;
  if (threadIdx.x == 0) cnt = 0;
  __syncthreads();
  unsigned int lo = w[threadIdx.x] & 0xFFFFu;
  unsigned int ex = (lo >> 7) & 0xFFu;
  int wild = (ex < 103u || ex > 151u) ? 1 : 0;
  if (lo == 0u || lo == 0x8000u) wild = 0;
  atomicAdd(&cnt, wild);
  __syncthreads();
  if (threadIdx.x == 0) flag[0] = (cnt > 64) ? 1 : 0;
}

// ---- fused: hx->fp32, dst-degree (float), src-histogram (int) ----
__global__ void k_pre(const void* __restrict__ hx_in, float* __restrict__ hx32,
                      const int* __restrict__ src, const int* __restrict__ dst,
                      float* __restrict__ deg, int* __restrict__ hist,
                      const int* __restrict__ flag) {
  int isf32 = flag[0];
  int idx = blockIdx.x * 256 + threadIdx.x;      // grid = E = N*NC exactly
  hx32[idx] = loadf(hx_in, idx, isf32);
  atomicAdd(&deg[dst[idx]], 1.0f);
  atomicAdd(&hist[src[idx]], 1);
}

// ---- in-place exclusive scan of hist[N_NODES] (single block, 256 threads) ----
__global__ void k_scan(int* __restrict__ hist) {
  __shared__ int tot[256];
  int t = threadIdx.x;
  int lo = t * 196, hi = lo + 196; if (hi > N_NODES) hi = N_NODES;
  int s = 0;
  for (int i = lo; i < hi; i++) s += hist[i];
  tot[t] = s;
  __syncthreads();
  if (t == 0) { int run = 0; for (int i = 0; i < 256; i++) { int v = tot[i]; tot[i] = run; run += v; } }
  __syncthreads();
  int run = tot[t];
  for (int i = lo; i < hi; i++) { int v = hist[i]; hist[i] = run; run += v; }
}

// ---- scatter edges into src-sorted order; hist holds running cursors ----
__global__ void k_scatter(const int* __restrict__ src, const int* __restrict__ dst,
                          int* __restrict__ cursors, uint_t* __restrict__ srcdst,
                          int* __restrict__ eid) {
  int e = blockIdx.x * 256 + threadIdx.x;
  int s = src[e];
  int p = atomicAdd(&cursors[s], 1);
  srcdst[p] = ((uint_t)s << 16) | (uint_t)dst[e];   // both < 65536
  eid[p] = e;
}

// ---- per-node projection table (bf16) + zero agg ----
__global__ void k_rnode(const float* __restrict__ hx, const void* __restrict__ w2,
                        const void* __restrict__ b2, ushort_t* __restrict__ Rt,
                        float* __restrict__ agg, const int* __restrict__ flag) {
  __shared__ float w2t[256 * 36];   // [io][h], padded 32->36
  __shared__ float b2s[256];
  int isf32 = flag[0];
  int tid = threadIdx.x;
  for (int k = tid; k < 256 * HID; k += 256) {
    int h = k >> 8, io = k & 255;
    w2t[io * 36 + h] = loadf(w2, h * 256 + io, isf32);
  }
  b2s[tid] = loadf(b2, tid, isf32);
  __syncthreads();
  int idx = blockIdx.x * 256 + tid;               // grid = N*NC exactly
  agg[idx] = 0.0f;
  int node = idx >> 4, o = idx & 15;

  float hxr[16];
  const float4* hp = (const float4*)(hx + node * NC);
  #pragma unroll
  for (int q = 0; q < 4; q++) {
    float4 t = hp[q];
    hxr[4 * q + 0] = t.x; hxr[4 * q + 1] = t.y; hxr[4 * q + 2] = t.z; hxr[4 * q + 3] = t.w;
  }

  ushort_t* rowp = Rt + (size_t)node * RT_ROW;
  #pragma unroll
  for (int c = 0; c < 4; c++) {
    float a[8] = {0, 0, 0, 0, 0, 0, 0, 0};
    #pragma unroll
    for (int i = 0; i < 16; i++) {
      const float* wp = &w2t[(i * 16 + o) * 36 + c * 8];
      float4 wa = *(const float4*)(wp);
      float4 wb = *(const float4*)(wp + 4);
      a[0] += hxr[i] * wa.x; a[1] += hxr[i] * wa.y; a[2] += hxr[i] * wa.z; a[3] += hxr[i] * wa.w;
      a[4] += hxr[i] * wb.x; a[5] += hxr[i] * wb.y; a[6] += hxr[i] * wb.z; a[7] += hxr[i] * wb.w;
    }
    u16x8 ov;
    #pragma unroll
    for (int j = 0; j < 8; j++) ov[j] = f2bf(a[j]);
    *(u16x8*)(rowp + o * 32 + c * 8) = ov;
  }
  float vb = 0.0f;
  #pragma unroll
  for (int i = 0; i < 16; i++) vb += hxr[i] * b2s[i * 16 + o];
  rowp[512 + o] = f2bf(vb);
}

// ---- edge kernel: recompute hidden in LDS, dot with gathered Rt, scatter ----
__global__ void __launch_bounds__(256) k_msg(
    const int* __restrict__ src, const int* __restrict__ dst,
    const uint_t* __restrict__ srcdst, const int* __restrict__ eid,
    const void* __restrict__ ef, const void* __restrict__ w1,
    const void* __restrict__ b1, const ushort_t* __restrict__ Rt,
    float* __restrict__ agg, const int* __restrict__ flag, int sorted) {
  __shared__ float w1s[FDIM * HID];
  __shared__ float b1s[HID];
  __shared__ float efs[EPB * FDIM];
  __shared__ float hs[EPB * 33];
  __shared__ int ssrc[EPB], sdst[EPB], seid[EPB];

  int isf32 = flag[0];
  int tid = threadIdx.x;
  int e0 = blockIdx.x * EPB;

  for (int k = tid; k < FDIM * HID; k += 256) w1s[k] = loadf(w1, k, isf32);
  if (tid < HID) b1s[tid] = loadf(b1, tid, isf32);
  if (tid < EPB) {
    if (sorted) {
      uint_t sd = srcdst[e0 + tid];
      ssrc[tid] = (int)(sd >> 16); sdst[tid] = (int)(sd & 0xFFFFu);
      seid[tid] = eid[e0 + tid];
    } else {
      ssrc[tid] = src[e0 + tid]; sdst[tid] = dst[e0 + tid]; seid[tid] = e0 + tid;
    }
  }
  __syncthreads();

  // stage edge features (gather by original edge id)
  #pragma unroll
  for (int q = 0; q < 4; q++) {
    int j = q * 256 + tid;
    int le = j >> 4, i = j & 15;
    if (i < FDIM) efs[le * FDIM + i] = loadf(ef, seid[le] * FDIM + i, isf32);
  }
  __syncthreads();

  // hidden[le,h] = relu(ef @ W1 + b1), fp32 in LDS
  for (int v = tid; v < EPB * HID; v += 256) {
    int le = v >> 5, h = v & 31;
    float acc = b1s[h];
    #pragma unroll
    for (int i = 0; i < FDIM; i++) acc += efs[le * FDIM + i] * w1s[i * HID + h];
    hs[le * 33 + h] = fmaxf(acc, 0.0f);
  }
  __syncthreads();

  #pragma unroll
  for (int q = 0; q < 4; q++) {
    int item = q * 256 + tid;
    int le = item >> 4, o = item & 15;
    int s = ssrc[le], d = sdst[le];
    const ushort_t* rrow = Rt + (size_t)s * RT_ROW;
    const u16x8* rr = (const u16x8*)(rrow + o * 32);
    float acc = bf2f(rrow[512 + o]);
    #pragma unroll
    for (int c = 0; c < 4; c++) {
      u16x8 rv = rr[c];
      #pragma unroll
      for (int j = 0; j < 8; j++) acc += hs[le * 33 + c * 8 + j] * bf2f(rv[j]);
    }
    atomicAdd(&agg[d * NC + o], acc);
  }
}

// ---- GRU cell, in-place on hx32; inv-deg inlined ----
__global__ void k_gru(const float* __restrict__ agg, const float* __restrict__ deg,
                      float* __restrict__ hx, const void* __restrict__ w_ih,
                      const void* __restrict__ w_hh, const void* __restrict__ b_ih,
                      const void* __restrict__ b_hh, void* __restrict__ out,
                      int write_out, const int* __restrict__ flag) {
  __shared__ float wih[3 * NC * NC], whh[3 * NC * NC], bih[3 * NC], bhh[3 * NC];
  int isf32 = flag[0];
  int tid = threadIdx.x;
  for (int k = tid; k < 3 * NC * NC; k += 256) {
    wih[k] = loadf(w_ih, k, isf32);
    whh[k] = loadf(w_hh, k, isf32);
  }
  if (tid < 3 * NC) { bih[tid] = loadf(b_ih, tid, isf32); bhh[tid] = loadf(b_hh, tid, isf32); }
  __syncthreads();
  int idx = blockIdx.x * 256 + tid;               // grid = N*NC exactly
  int v = idx >> 4, o = idx & 15;
  float inv = 1.0f / fmaxf(deg[v], 1.0f);
  float x[16], h[16];
  const float4* ar = (const float4*)(agg + v * NC);
  const float4* hr = (const float4*)(hx + v * NC);
  #pragma unroll
  for (int q = 0; q < 4; q++) {
    float4 a = ar[q], b = hr[q];
    x[4 * q + 0] = a.x * inv; x[4 * q + 1] = a.y * inv; x[4 * q + 2] = a.z * inv; x[4 * q + 3] = a.w * inv;
    h[4 * q + 0] = b.x; h[4 * q + 1] = b.y; h[4 * q + 2] = b.z; h[4 * q + 3] = b.w;
  }
  float gir = bih[o], giz = bih[NC + o], gin = bih[2 * NC + o];
  float ghr = bhh[o], ghz = bhh[NC + o], ghn = bhh[2 * NC + o];
  #pragma unroll
  for (int k = 0; k < NC; k++) {
    gir += x[k] * wih[o * NC + k];
    giz += x[k] * wih[(NC + o) * NC + k];
    gin += x[k] * wih[(2 * NC + o) * NC + k];
    ghr += h[k] * whh[o * NC + k];
    ghz += h[k] * whh[(NC + o) * NC + k];
    ghn += h[k] * whh[(2 * NC + o) * NC + k];
  }
  float r = sigmoidf_(gir + ghr);
  float z = sigmoidf_(giz + ghz);
  float n = tanhf_(gin + r * ghn);
  float hn = (1.0f - z) * n + z * h[o];
  __syncthreads();          // all reads of hx row done before any write (in-place)
  hx[idx] = hn;
  if (write_out) {
    if (isf32) ((float*)out)[idx] = hn;
    else       ((ushort_t*)out)[idx] = f2bf(hn);
  }
}

extern "C" void kernel_launch(void* const* d_in, const int* in_sizes, int n_in,
                              void* d_out, int out_size, void* d_ws, size_t ws_size,
                              hipStream_t stream) {
  const void* hx_in = d_in[0];
  const void* ef    = d_in[1];
  const int*  esrc  = (const int*)d_in[2];
  const int*  edst  = (const int*)d_in[3];
  const void* w1    = d_in[4];
  const void* b1    = d_in[5];
  const void* w2    = d_in[6];
  const void* b2    = d_in[7];
  const void* wih   = d_in[8];
  const void* whh   = d_in[9];
  const void* bih   = d_in[10];
  const void* bhh   = d_in[11];

  // layout (deg and hist contiguous -> one memset covers both)
  char* ws = (char*)d_ws;
  float*    hx32 = (float*)(ws + 0);           //  3,200,000
  float*    agg  = (float*)(ws + 3200000);     //  3,200,000
  float*    deg  = (float*)(ws + 6400000);     //    200,064
  int*      hist = (int*)  (ws + 6600064);     //    200,064
  int*      flag = (int*)  (ws + 6800128);     //        256
  int sorted = (ws_size >= (size_t)66100000) ? 1 : 0;
  uint_t* srcdst; int* eid; ushort_t* Rt;
  if (sorted) {
    srcdst = (uint_t*)(ws + 6800384);          //  3,200,000
    eid    = (int*)   (ws + 10000384);         //  3,200,000
    Rt     = (ushort_t*)(ws + 13200384);       // 52,800,000 -> ends 66,000,384
  } else {
    srcdst = (uint_t*)(ws + 6800384);          // unused in kernels (sorted=0)
    eid    = (int*)   (ws + 6800384);
    Rt     = (ushort_t*)(ws + 6800640);        // 52,800,000 -> ends 59,600,640
  }

  k_detect<<<1, 256, 0, stream>>>((const unsigned int*)hx_in, flag);
  hipMemsetAsync(deg, 0, 400128, stream);      // deg + hist
  k_pre<<<N_EDGES / 256, 256, 0, stream>>>(hx_in, hx32, esrc, edst, deg, hist, flag);
  if (sorted) {
    k_scan<<<1, 256, 0, stream>>>(hist);
    k_scatter<<<N_EDGES / 256, 256, 0, stream>>>(esrc, edst, hist, srcdst, eid);
  }

  for (int r = 0; r < 2; r++) {
    k_rnode<<<(N_NODES * NC) / 256, 256, 0, stream>>>(hx32, w2, b2, Rt, agg, flag);
    k_msg<<<N_EDGES / EPB, 256, 0, stream>>>(esrc, edst, srcdst, eid, ef, w1, b1,
                                             Rt, agg, flag, sorted);
    k_gru<<<(N_NODES * NC) / 256, 256, 0, stream>>>(agg, deg, hx32,
                                                    wih, whh, bih, bhh, d_out, r == 1, flag);
  }
}

// Round 5
// 511.463 us; speedup vs baseline: 1.1423x; 1.1423x over previous
//
#include <hip/hip_runtime.h>
#include <hip/hip_bf16.h>

#define N_NODES 50000
#define N_EDGES 800000
#define NC 16
#define FDIM 13
#define HID 32
#define RT_ROW 528     // 16 outputs * 32 hidden + 16 b2-terms (bf16)
#define EPB 64         // edges per block in k_msg
#define BSHIFT 3       // nodes per bucket = 8
#define NBUCK 6400     // ceil(50000/8)=6250, padded to 256*25
#define ZWORDS 56400   // deg(50000) + hist(6400) ints to zero

typedef unsigned short ushort_t;
typedef unsigned int uint_t;
typedef __attribute__((ext_vector_type(8))) unsigned short u16x8;

__device__ __forceinline__ float bf2f(ushort_t u) {
  union { unsigned int i; float f; } v; v.i = ((unsigned int)u) << 16; return v.f;
}
__device__ __forceinline__ ushort_t f2bf(float f) {
  union { unsigned int i; float f; } v; v.f = f;
  unsigned int r = v.i + 0x7FFFu + ((v.i >> 16) & 1u);   // RNE
  return (ushort_t)(r >> 16);
}
__device__ __forceinline__ float loadf(const void* p, int i, int isf32) {
  return isf32 ? ((const float*)p)[i] : bf2f(((const ushort_t*)p)[i]);
}
__device__ __forceinline__ float sigmoidf_(float x) { return 1.0f / (1.0f + __expf(-x)); }
__device__ __forceinline__ float tanhf_(float x) { return 1.0f - 2.0f / (__expf(2.0f * x) + 1.0f); }

// ---- fused: zero deg+hist region; block 0 also runs the dtype detector ----
__global__ void k_init(const unsigned int* __restrict__ hx_words, int* __restrict__ flag,
                       int* __restrict__ zbase) {
  int idx = blockIdx.x * 256 + threadIdx.x;
  if (idx < ZWORDS) zbase[idx] = 0;
  if (blockIdx.x == 0) {
    __shared__ int cnt;
    if (threadIdx.x == 0) cnt = 0;
    __syncthreads();
    unsigned int lo = hx_words[threadIdx.x] & 0xFFFFu;
    unsigned int ex = (lo >> 7) & 0xFFu;
    int wild = (ex < 103u || ex > 151u) ? 1 : 0;
    if (lo == 0u || lo == 0x8000u) wild = 0;
    atomicAdd(&cnt, wild);
    __syncthreads();
    if (threadIdx.x == 0) flag[0] = (cnt > 64) ? 1 : 0;   // 1 = fp32 inputs
  }
}

// ---- fused: hx->fp32 copy, dst-degree (float), src-bucket histogram ----
__global__ void k_pre(const void* __restrict__ hx_in, float* __restrict__ hx32,
                      const int* __restrict__ src, const int* __restrict__ dst,
                      float* __restrict__ deg, int* __restrict__ hist,
                      const int* __restrict__ flag) {
  int isf32 = flag[0];
  int idx = blockIdx.x * 256 + threadIdx.x;      // grid = E = N*NC exactly
  hx32[idx] = loadf(hx_in, idx, isf32);
  atomicAdd(&deg[dst[idx]], 1.0f);
  atomicAdd(&hist[src[idx] >> BSHIFT], 1);
}

// ---- single-block LDS scan of hist[NBUCK] (exclusive) ----
__global__ void k_scan(int* __restrict__ hist) {
  __shared__ int lds[NBUCK];      // 25.6 KB
  __shared__ int psum[256];
  int t = threadIdx.x;
  for (int i = t; i < NBUCK; i += 256) lds[i] = hist[i];
  __syncthreads();
  int base = t * 25;              // stride 25 (odd) -> conflict-free
  int s = 0;
  #pragma unroll
  for (int i = 0; i < 25; i++) { int v = lds[base + i]; lds[base + i] = s; s += v; }
  psum[t] = s;
  __syncthreads();
  if (t == 0) { int run = 0; for (int i = 0; i < 256; i++) { int v = psum[i]; psum[i] = run; run += v; } }
  __syncthreads();
  int off = psum[t];
  #pragma unroll
  for (int i = 0; i < 25; i++) lds[base + i] += off;
  __syncthreads();
  for (int i = t; i < NBUCK; i += 256) hist[i] = lds[i];
}

// ---- scatter edges into bucket order (hist = running cursors); packed uint2 ----
__global__ void k_scatter(const int* __restrict__ src, const int* __restrict__ dst,
                          int* __restrict__ cursors, uint2* __restrict__ sortbuf) {
  int e = blockIdx.x * 256 + threadIdx.x;
  int s = src[e];
  int p = atomicAdd(&cursors[s >> BSHIFT], 1);
  uint2 rec; rec.x = ((uint_t)s << 16) | (uint_t)dst[e]; rec.y = (uint_t)e;
  sortbuf[p] = rec;
}

// ---- Rt from hx32 (initial repeat) + zero agg ----
__global__ void k_rnode(const float* __restrict__ hx, const void* __restrict__ w2,
                        const void* __restrict__ b2, ushort_t* __restrict__ Rt,
                        float* __restrict__ agg, const int* __restrict__ flag) {
  __shared__ float w2t[256 * 36];   // [io][h], padded 32->36
  __shared__ float b2s[256];
  int isf32 = flag[0];
  int tid = threadIdx.x;
  for (int k = tid; k < 256 * HID; k += 256) {
    int h = k >> 8, io = k & 255;
    w2t[io * 36 + h] = loadf(w2, h * 256 + io, isf32);
  }
  b2s[tid] = loadf(b2, tid, isf32);
  __syncthreads();
  int idx = blockIdx.x * 256 + tid;               // grid = N*NC exactly
  agg[idx] = 0.0f;
  int node = idx >> 4, o = idx & 15;

  float hxr[16];
  const float4* hp = (const float4*)(hx + node * NC);
  #pragma unroll
  for (int q = 0; q < 4; q++) {
    float4 t = hp[q];
    hxr[4 * q + 0] = t.x; hxr[4 * q + 1] = t.y; hxr[4 * q + 2] = t.z; hxr[4 * q + 3] = t.w;
  }
  ushort_t* rowp = Rt + (size_t)node * RT_ROW;
  #pragma unroll
  for (int c = 0; c < 4; c++) {
    float a[8] = {0, 0, 0, 0, 0, 0, 0, 0};
    #pragma unroll
    for (int i = 0; i < 16; i++) {
      const float* wp = &w2t[(i * 16 + o) * 36 + c * 8];
      float4 wa = *(const float4*)(wp);
      float4 wb = *(const float4*)(wp + 4);
      a[0] += hxr[i] * wa.x; a[1] += hxr[i] * wa.y; a[2] += hxr[i] * wa.z; a[3] += hxr[i] * wa.w;
      a[4] += hxr[i] * wb.x; a[5] += hxr[i] * wb.y; a[6] += hxr[i] * wb.z; a[7] += hxr[i] * wb.w;
    }
    u16x8 ov;
    #pragma unroll
    for (int j = 0; j < 8; j++) ov[j] = f2bf(a[j]);
    *(u16x8*)(rowp + o * 32 + c * 8) = ov;
  }
  float vb = 0.0f;
  #pragma unroll
  for (int i = 0; i < 16; i++) vb += hxr[i] * b2s[i * 16 + o];
  rowp[512 + o] = f2bf(vb);
}

// ---- edge kernel: recompute hidden in LDS, dot with gathered Rt, scatter ----
__global__ void __launch_bounds__(256) k_msg(
    const int* __restrict__ src, const int* __restrict__ dst,
    const uint2* __restrict__ sortbuf, const void* __restrict__ ef,
    const void* __restrict__ w1, const void* __restrict__ b1,
    const ushort_t* __restrict__ Rt, float* __restrict__ agg,
    const int* __restrict__ flag, int sorted) {
  __shared__ float w1s[FDIM * HID];
  __shared__ float b1s[HID];
  __shared__ float efs[EPB * FDIM];
  __shared__ float hs[EPB * 33];
  __shared__ int ssrc[EPB], sdst[EPB], seid[EPB];

  int isf32 = flag[0];
  int tid = threadIdx.x;
  int e0 = blockIdx.x * EPB;

  for (int k = tid; k < FDIM * HID; k += 256) w1s[k] = loadf(w1, k, isf32);
  if (tid < HID) b1s[tid] = loadf(b1, tid, isf32);
  if (tid < EPB) {
    if (sorted) {
      uint2 rec = sortbuf[e0 + tid];
      ssrc[tid] = (int)(rec.x >> 16); sdst[tid] = (int)(rec.x & 0xFFFFu);
      seid[tid] = (int)rec.y;
    } else {
      ssrc[tid] = src[e0 + tid]; sdst[tid] = dst[e0 + tid]; seid[tid] = e0 + tid;
    }
  }
  __syncthreads();

  #pragma unroll
  for (int q = 0; q < 4; q++) {
    int j = q * 256 + tid;
    int le = j >> 4, i = j & 15;
    if (i < FDIM) efs[le * FDIM + i] = loadf(ef, seid[le] * FDIM + i, isf32);
  }
  __syncthreads();

  for (int v = tid; v < EPB * HID; v += 256) {
    int le = v >> 5, h = v & 31;
    float acc = b1s[h];
    #pragma unroll
    for (int i = 0; i < FDIM; i++) acc += efs[le * FDIM + i] * w1s[i * HID + h];
    hs[le * 33 + h] = fmaxf(acc, 0.0f);
  }
  __syncthreads();

  #pragma unroll
  for (int q = 0; q < 4; q++) {
    int item = q * 256 + tid;
    int le = item >> 4, o = item & 15;
    int s = ssrc[le], d = sdst[le];
    const ushort_t* rrow = Rt + (size_t)s * RT_ROW;
    const u16x8* rr = (const u16x8*)(rrow + o * 32);
    float acc = bf2f(rrow[512 + o]);
    #pragma unroll
    for (int c = 0; c < 4; c++) {
      u16x8 rv = rr[c];
      #pragma unroll
      for (int j = 0; j < 8; j++) acc += hs[le * 33 + c * 8 + j] * bf2f(rv[j]);
    }
    atomicAdd(&agg[d * NC + o], acc);
  }
}

// ---- fused GRU + Rt rebuild + agg re-zero (middle repeats) ----
__global__ void k_update(const float* __restrict__ agg_in, const float* __restrict__ deg,
                         float* __restrict__ hx, const void* __restrict__ w_ih,
                         const void* __restrict__ w_hh, const void* __restrict__ b_ih,
                         const void* __restrict__ b_hh, const void* __restrict__ w2,
                         const void* __restrict__ b2, ushort_t* __restrict__ Rt,
                         float* __restrict__ agg_out, const int* __restrict__ flag) {
  __shared__ float w2t[256 * 36];
  __shared__ float b2s[256];
  __shared__ float wih[3 * NC * NC], whh[3 * NC * NC], bih[3 * NC], bhh[3 * NC];
  __shared__ float hx_l[16 * 17];
  int isf32 = flag[0];
  int tid = threadIdx.x;
  for (int k = tid; k < 256 * HID; k += 256) {
    int h = k >> 8, io = k & 255;
    w2t[io * 36 + h] = loadf(w2, h * 256 + io, isf32);
  }
  b2s[tid] = loadf(b2, tid, isf32);
  for (int k = tid; k < 3 * NC * NC; k += 256) {
    wih[k] = loadf(w_ih, k, isf32);
    whh[k] = loadf(w_hh, k, isf32);
  }
  if (tid < 3 * NC) { bih[tid] = loadf(b_ih, tid, isf32); bhh[tid] = loadf(b_hh, tid, isf32); }
  __syncthreads();

  int idx = blockIdx.x * 256 + tid;               // grid = N*NC exactly
  int v = idx >> 4, o = idx & 15, vl = tid >> 4;
  float inv = 1.0f / fmaxf(deg[v], 1.0f);
  float x[16], h[16];
  const float4* ar = (const float4*)(agg_in + v * NC);
  const float4* hr = (const float4*)(hx + v * NC);
  #pragma unroll
  for (int q = 0; q < 4; q++) {
    float4 a = ar[q], b = hr[q];
    x[4 * q + 0] = a.x * inv; x[4 * q + 1] = a.y * inv; x[4 * q + 2] = a.z * inv; x[4 * q + 3] = a.w * inv;
    h[4 * q + 0] = b.x; h[4 * q + 1] = b.y; h[4 * q + 2] = b.z; h[4 * q + 3] = b.w;
  }
  float gir = bih[o], giz = bih[NC + o], gin = bih[2 * NC + o];
  float ghr = bhh[o], ghz = bhh[NC + o], ghn = bhh[2 * NC + o];
  #pragma unroll
  for (int k = 0; k < NC; k++) {
    gir += x[k] * wih[o * NC + k];
    giz += x[k] * wih[(NC + o) * NC + k];
    gin += x[k] * wih[(2 * NC + o) * NC + k];
    ghr += h[k] * whh[o * NC + k];
    ghz += h[k] * whh[(NC + o) * NC + k];
    ghn += h[k] * whh[(2 * NC + o) * NC + k];
  }
  float r = sigmoidf_(gir + ghr);
  float z = sigmoidf_(giz + ghz);
  float n = tanhf_(gin + r * ghn);
  float hn = (1.0f - z) * n + z * h[o];
  hx_l[vl * 17 + o] = hn;
  __syncthreads();          // hx row fully read + staged before in-place write
  hx[idx] = hn;
  agg_out[idx] = 0.0f;

  float hxr[16];
  #pragma unroll
  for (int i = 0; i < 16; i++) hxr[i] = hx_l[vl * 17 + i];
  ushort_t* rowp = Rt + (size_t)v * RT_ROW;
  #pragma unroll
  for (int c = 0; c < 4; c++) {
    float a[8] = {0, 0, 0, 0, 0, 0, 0, 0};
    #pragma unroll
    for (int i = 0; i < 16; i++) {
      const float* wp = &w2t[(i * 16 + o) * 36 + c * 8];
      float4 wa = *(const float4*)(wp);
      float4 wb = *(const float4*)(wp + 4);
      a[0] += hxr[i] * wa.x; a[1] += hxr[i] * wa.y; a[2] += hxr[i] * wa.z; a[3] += hxr[i] * wa.w;
      a[4] += hxr[i] * wb.x; a[5] += hxr[i] * wb.y; a[6] += hxr[i] * wb.z; a[7] += hxr[i] * wb.w;
    }
    u16x8 ov;
    #pragma unroll
    for (int j = 0; j < 8; j++) ov[j] = f2bf(a[j]);
    *(u16x8*)(rowp + o * 32 + c * 8) = ov;
  }
  float vb = 0.0f;
  #pragma unroll
  for (int i = 0; i < 16; i++) vb += hxr[i] * b2s[i * 16 + o];
  rowp[512 + o] = f2bf(vb);
}

// ---- final GRU: writes d_out only ----
__global__ void k_gru(const float* __restrict__ agg, const float* __restrict__ deg,
                      const float* __restrict__ hx, const void* __restrict__ w_ih,
                      const void* __restrict__ w_hh, const void* __restrict__ b_ih,
                      const void* __restrict__ b_hh, void* __restrict__ out,
                      const int* __restrict__ flag) {
  __shared__ float wih[3 * NC * NC], whh[3 * NC * NC], bih[3 * NC], bhh[3 * NC];
  int isf32 = flag[0];
  int tid = threadIdx.x;
  for (int k = tid; k < 3 * NC * NC; k += 256) {
    wih[k] = loadf(w_ih, k, isf32);
    whh[k] = loadf(w_hh, k, isf32);
  }
  if (tid < 3 * NC) { bih[tid] = loadf(b_ih, tid, isf32); bhh[tid] = loadf(b_hh, tid, isf32); }
  __syncthreads();
  int idx = blockIdx.x * 256 + tid;
  int v = idx >> 4, o = idx & 15;
  float inv = 1.0f / fmaxf(deg[v], 1.0f);
  float x[16], h[16];
  const float4* ar = (const float4*)(agg + v * NC);
  const float4* hr = (const float4*)(hx + v * NC);
  #pragma unroll
  for (int q = 0; q < 4; q++) {
    float4 a = ar[q], b = hr[q];
    x[4 * q + 0] = a.x * inv; x[4 * q + 1] = a.y * inv; x[4 * q + 2] = a.z * inv; x[4 * q + 3] = a.w * inv;
    h[4 * q + 0] = b.x; h[4 * q + 1] = b.y; h[4 * q + 2] = b.z; h[4 * q + 3] = b.w;
  }
  float gir = bih[o], giz = bih[NC + o], gin = bih[2 * NC + o];
  float ghr = bhh[o], ghz = bhh[NC + o], ghn = bhh[2 * NC + o];
  #pragma unroll
  for (int k = 0; k < NC; k++) {
    gir += x[k] * wih[o * NC + k];
    giz += x[k] * wih[(NC + o) * NC + k];
    gin += x[k] * wih[(2 * NC + o) * NC + k];
    ghr += h[k] * whh[o * NC + k];
    ghz += h[k] * whh[(NC + o) * NC + k];
    ghn += h[k] * whh[(2 * NC + o) * NC + k];
  }
  float r = sigmoidf_(gir + ghr);
  float z = sigmoidf_(giz + ghz);
  float n = tanhf_(gin + r * ghn);
  float hn = (1.0f - z) * n + z * h[o];
  if (isf32) ((float*)out)[idx] = hn;
  else       ((ushort_t*)out)[idx] = f2bf(hn);
}

extern "C" void kernel_launch(void* const* d_in, const int* in_sizes, int n_in,
                              void* d_out, int out_size, void* d_ws, size_t ws_size,
                              hipStream_t stream) {
  const void* hx_in = d_in[0];
  const void* ef    = d_in[1];
  const int*  esrc  = (const int*)d_in[2];
  const int*  edst  = (const int*)d_in[3];
  const void* w1    = d_in[4];
  const void* b1    = d_in[5];
  const void* w2    = d_in[6];
  const void* b2    = d_in[7];
  const void* wih   = d_in[8];
  const void* whh   = d_in[9];
  const void* bih   = d_in[10];
  const void* bhh   = d_in[11];

  char* ws = (char*)d_ws;
  float*    hx32 = (float*)(ws + 0);           //  3,200,000
  float*    agg  = (float*)(ws + 3200000);     //  3,200,000
  int*      flag = (int*)  (ws + 6400000);     //        256
  float*    deg  = (float*)(ws + 6400256);     //    200,000
  int*      hist = (int*)  (ws + 6600256);     //     25,600  (deg+hist = zero region)
  int sorted = (ws_size >= (size_t)65826112) ? 1 : 0;
  uint2* sortbuf; ushort_t* Rt;
  if (sorted) {
    sortbuf = (uint2*)(ws + 6625856);          //  6,400,000
    Rt      = (ushort_t*)(ws + 13025856);      // 52,800,000 -> ends 65,825,856
  } else {
    sortbuf = (uint2*)(ws + 6625856);          // unused (sorted=0)
    Rt      = (ushort_t*)(ws + 6625856);       // -> ends 59,425,856
  }

  k_init<<<(ZWORDS + 255) / 256, 256, 0, stream>>>((const unsigned int*)hx_in, flag, (int*)deg);
  k_pre<<<N_EDGES / 256, 256, 0, stream>>>(hx_in, hx32, esrc, edst, deg, hist, flag);
  if (sorted) {
    k_scan<<<1, 256, 0, stream>>>(hist);
    k_scatter<<<N_EDGES / 256, 256, 0, stream>>>(esrc, edst, hist, sortbuf);
  }

  k_rnode<<<(N_NODES * NC) / 256, 256, 0, stream>>>(hx32, w2, b2, Rt, agg, flag);
  k_msg<<<N_EDGES / EPB, 256, 0, stream>>>(esrc, edst, sortbuf, ef, w1, b1, Rt, agg, flag, sorted);
  k_update<<<(N_NODES * NC) / 256, 256, 0, stream>>>(agg, deg, hx32, wih, whh, bih, bhh,
                                                     w2, b2, Rt, agg, flag);
  k_msg<<<N_EDGES / EPB, 256, 0, stream>>>(esrc, edst, sortbuf, ef, w1, b1, Rt, agg, flag, sorted);
  k_gru<<<(N_NODES * NC) / 256, 256, 0, stream>>>(agg, deg, hx32, wih, whh, bih, bhh, d_out, flag);
}

// Round 6
// 489.871 us; speedup vs baseline: 1.1926x; 1.0441x over previous
//
#include <hip/hip_runtime.h>
#include <hip/hip_bf16.h>

#define N_NODES 50000
#define N_EDGES 800000
#define NC 16
#define FDIM 13
#define HID 32
#define RT_ROW 528     // 16 outputs * 32 hidden + 16 b2-terms (bf16)
#define EPB 64         // edges per block in msg kernels
#define BSHIFT 3       // nodes per bucket = 8
#define NBUCK 6400     // ceil(50000/8)=6250 padded to 256*25
#define ZWORDS 56400   // deg(50000) + hist(6400) ints to zero

typedef unsigned short ushort_t;
typedef unsigned int uint_t;
typedef __attribute__((ext_vector_type(8))) unsigned short u16x8;

__device__ __forceinline__ float bf2f(ushort_t u) {
  union { unsigned int i; float f; } v; v.i = ((unsigned int)u) << 16; return v.f;
}
__device__ __forceinline__ ushort_t f2bf(float f) {
  union { unsigned int i; float f; } v; v.f = f;
  unsigned int r = v.i + 0x7FFFu + ((v.i >> 16) & 1u);   // RNE
  return (ushort_t)(r >> 16);
}
__device__ __forceinline__ float loadf(const void* p, int i, int isf32) {
  return isf32 ? ((const float*)p)[i] : bf2f(((const ushort_t*)p)[i]);
}
__device__ __forceinline__ float sigmoidf_(float x) { return 1.0f / (1.0f + __expf(-x)); }
__device__ __forceinline__ float tanhf_(float x) { return 1.0f - 2.0f / (__expf(2.0f * x) + 1.0f); }

// ---- zero deg+hist; block 0 also runs the dtype detector ----
__global__ void k_init(const unsigned int* __restrict__ hx_words, int* __restrict__ flag,
                       int* __restrict__ zbase) {
  int idx = blockIdx.x * 256 + threadIdx.x;
  if (idx < ZWORDS) zbase[idx] = 0;
  if (blockIdx.x == 0) {
    __shared__ int cnt;
    if (threadIdx.x == 0) cnt = 0;
    __syncthreads();
    unsigned int lo = hx_words[threadIdx.x] & 0xFFFFu;
    unsigned int ex = (lo >> 7) & 0xFFu;
    int wild = (ex < 103u || ex > 151u) ? 1 : 0;
    if (lo == 0u || lo == 0x8000u) wild = 0;
    atomicAdd(&cnt, wild);
    __syncthreads();
    if (threadIdx.x == 0) flag[0] = (cnt > 64) ? 1 : 0;   // 1 = fp32 inputs
  }
}

// ---- hx->fp32 copy, dst-degree, src-bucket histogram (grid = E/256 = N*NC/256) ----
__global__ void k_pre(const void* __restrict__ hx_in, float* __restrict__ hx32,
                      const int* __restrict__ src, const int* __restrict__ dst,
                      float* __restrict__ deg, int* __restrict__ hist,
                      const int* __restrict__ flag) {
  int isf32 = flag[0];
  int idx = blockIdx.x * 256 + threadIdx.x;
  hx32[idx] = loadf(hx_in, idx, isf32);
  atomicAdd(&deg[dst[idx]], 1.0f);
  atomicAdd(&hist[src[idx] >> BSHIFT], 1);
}

// ---- fused: block 0 = exclusive scan of hist; blocks 1.. = Rt build + agg zero ----
__global__ void k_scan_rnode(int* __restrict__ hist, const float* __restrict__ hx,
                             const void* __restrict__ w2, const void* __restrict__ b2,
                             ushort_t* __restrict__ Rt, float* __restrict__ agg,
                             const int* __restrict__ flag, int sorted) {
  __shared__ int lds[NBUCK];
  __shared__ int psum[256];
  __shared__ float w2t[256 * 36];
  __shared__ float b2s[256];
  int tid = threadIdx.x;
  if (blockIdx.x == 0) {
    if (!sorted) return;
    for (int i = tid; i < NBUCK; i += 256) lds[i] = hist[i];
    __syncthreads();
    int base = tid * 25;
    int s = 0;
    #pragma unroll
    for (int i = 0; i < 25; i++) { int v = lds[base + i]; lds[base + i] = s; s += v; }
    psum[tid] = s;
    __syncthreads();
    if (tid == 0) { int run = 0; for (int i = 0; i < 256; i++) { int v = psum[i]; psum[i] = run; run += v; } }
    __syncthreads();
    int off = psum[tid];
    #pragma unroll
    for (int i = 0; i < 25; i++) lds[base + i] += off;
    __syncthreads();
    for (int i = tid; i < NBUCK; i += 256) hist[i] = lds[i];
    return;
  }
  // ---- rnode part ----
  int isf32 = flag[0];
  for (int k = tid; k < 256 * HID; k += 256) {
    int h = k >> 8, io = k & 255;
    w2t[io * 36 + h] = loadf(w2, h * 256 + io, isf32);
  }
  b2s[tid] = loadf(b2, tid, isf32);
  __syncthreads();
  int idx = (blockIdx.x - 1) * 256 + tid;        // covers N*NC exactly
  agg[idx] = 0.0f;
  int node = idx >> 4, o = idx & 15;

  float hxr[16];
  const float4* hp = (const float4*)(hx + node * NC);
  #pragma unroll
  for (int q = 0; q < 4; q++) {
    float4 t = hp[q];
    hxr[4 * q + 0] = t.x; hxr[4 * q + 1] = t.y; hxr[4 * q + 2] = t.z; hxr[4 * q + 3] = t.w;
  }
  ushort_t* rowp = Rt + (size_t)node * RT_ROW;
  #pragma unroll
  for (int c = 0; c < 4; c++) {
    float a[8] = {0, 0, 0, 0, 0, 0, 0, 0};
    #pragma unroll
    for (int i = 0; i < 16; i++) {
      const float* wp = &w2t[(i * 16 + o) * 36 + c * 8];
      float4 wa = *(const float4*)(wp);
      float4 wb = *(const float4*)(wp + 4);
      a[0] += hxr[i] * wa.x; a[1] += hxr[i] * wa.y; a[2] += hxr[i] * wa.z; a[3] += hxr[i] * wa.w;
      a[4] += hxr[i] * wb.x; a[5] += hxr[i] * wb.y; a[6] += hxr[i] * wb.z; a[7] += hxr[i] * wb.w;
    }
    u16x8 ov;
    #pragma unroll
    for (int j = 0; j < 8; j++) ov[j] = f2bf(a[j]);
    *(u16x8*)(rowp + o * 32 + c * 8) = ov;
  }
  float vb = 0.0f;
  #pragma unroll
  for (int i = 0; i < 16; i++) vb += hxr[i] * b2s[i * 16 + o];
  rowp[512 + o] = f2bf(vb);
}

// ---- mode2: scatter + filter-net MLP; writes srcdst (4B) + hidden bf16 (64B) sorted ----
__global__ void k_scatter_mlp(const int* __restrict__ src, const int* __restrict__ dst,
                              int* __restrict__ cursors, uint_t* __restrict__ srcdst,
                              ushort_t* __restrict__ hidden,
                              const void* __restrict__ ef, const void* __restrict__ w1,
                              const void* __restrict__ b1, const int* __restrict__ flag) {
  __shared__ float w1s[FDIM * HID];
  __shared__ float b1s[HID];
  int isf32 = flag[0];
  int tid = threadIdx.x;
  for (int k = tid; k < FDIM * HID; k += 256) w1s[k] = loadf(w1, k, isf32);
  if (tid < HID) b1s[tid] = loadf(b1, tid, isf32);
  __syncthreads();
  int e = blockIdx.x * 256 + tid;
  int s = src[e];
  int p = atomicAdd(&cursors[s >> BSHIFT], 1);
  srcdst[p] = ((uint_t)s << 16) | (uint_t)dst[e];
  float efr[FDIM];
  #pragma unroll
  for (int i = 0; i < FDIM; i++) efr[i] = loadf(ef, e * FDIM + i, isf32);
  u16x8* hrow = (u16x8*)(hidden + (size_t)p * HID);
  #pragma unroll
  for (int c = 0; c < 4; c++) {
    u16x8 ov;
    #pragma unroll
    for (int j = 0; j < 8; j++) {
      int h = c * 8 + j;
      float acc = b1s[h];
      #pragma unroll
      for (int i = 0; i < FDIM; i++) acc += efr[i] * w1s[i * HID + h];
      ov[j] = f2bf(fmaxf(acc, 0.0f));
    }
    hrow[c] = ov;
  }
}

// ---- mode1 scatter (R5-proven fallback) ----
__global__ void k_scatter1(const int* __restrict__ src, const int* __restrict__ dst,
                           int* __restrict__ cursors, uint2* __restrict__ sortbuf) {
  int e = blockIdx.x * 256 + threadIdx.x;
  int s = src[e];
  int p = atomicAdd(&cursors[s >> BSHIFT], 1);
  uint2 rec; rec.x = ((uint_t)s << 16) | (uint_t)dst[e]; rec.y = (uint_t)e;
  sortbuf[p] = rec;
}

// ---- mode2 edge kernel: stream sorted hidden, dot with Rt, scatter-add ----
__global__ void __launch_bounds__(256) k_msg2(
    const uint_t* __restrict__ srcdst, const ushort_t* __restrict__ hidden,
    const ushort_t* __restrict__ Rt, float* __restrict__ agg) {
  __shared__ float hs[EPB * 33];
  __shared__ int ssrc[EPB], sdst[EPB];
  int tid = threadIdx.x;
  int e0 = blockIdx.x * EPB;
  if (tid < EPB) {
    uint_t sd = srcdst[e0 + tid];
    ssrc[tid] = (int)(sd >> 16); sdst[tid] = (int)(sd & 0xFFFFu);
  }
  // stage hidden tile: 64 edges * 32 bf16 = 2048 ushorts = 256 * u16x8
  u16x8 hv = ((const u16x8*)(hidden + (size_t)e0 * HID))[tid];
  int le = tid >> 2, c0 = (tid & 3) * 8;
  #pragma unroll
  for (int j = 0; j < 8; j++) hs[le * 33 + c0 + j] = bf2f(hv[j]);
  __syncthreads();

  #pragma unroll
  for (int q = 0; q < 4; q++) {
    int item = q * 256 + tid;
    int e = item >> 4, o = item & 15;
    int s = ssrc[e], d = sdst[e];
    const ushort_t* rrow = Rt + (size_t)s * RT_ROW;
    const u16x8* rr = (const u16x8*)(rrow + o * 32);
    float acc = bf2f(rrow[512 + o]);
    #pragma unroll
    for (int c = 0; c < 4; c++) {
      u16x8 rv = rr[c];
      #pragma unroll
      for (int j = 0; j < 8; j++) acc += hs[e * 33 + c * 8 + j] * bf2f(rv[j]);
    }
    atomicAdd(&agg[d * NC + o], acc);
  }
}

// ---- mode1/0 edge kernel (R5-proven): recompute MLP in LDS ----
__global__ void __launch_bounds__(256) k_msg(
    const int* __restrict__ src, const int* __restrict__ dst,
    const uint2* __restrict__ sortbuf, const void* __restrict__ ef,
    const void* __restrict__ w1, const void* __restrict__ b1,
    const ushort_t* __restrict__ Rt, float* __restrict__ agg,
    const int* __restrict__ flag, int sorted) {
  __shared__ float w1s[FDIM * HID];
  __shared__ float b1s[HID];
  __shared__ float efs[EPB * FDIM];
  __shared__ float hs[EPB * 33];
  __shared__ int ssrc[EPB], sdst[EPB], seid[EPB];
  int isf32 = flag[0];
  int tid = threadIdx.x;
  int e0 = blockIdx.x * EPB;
  for (int k = tid; k < FDIM * HID; k += 256) w1s[k] = loadf(w1, k, isf32);
  if (tid < HID) b1s[tid] = loadf(b1, tid, isf32);
  if (tid < EPB) {
    if (sorted) {
      uint2 rec = sortbuf[e0 + tid];
      ssrc[tid] = (int)(rec.x >> 16); sdst[tid] = (int)(rec.x & 0xFFFFu);
      seid[tid] = (int)rec.y;
    } else {
      ssrc[tid] = src[e0 + tid]; sdst[tid] = dst[e0 + tid]; seid[tid] = e0 + tid;
    }
  }
  __syncthreads();
  #pragma unroll
  for (int q = 0; q < 4; q++) {
    int j = q * 256 + tid;
    int le = j >> 4, i = j & 15;
    if (i < FDIM) efs[le * FDIM + i] = loadf(ef, seid[le] * FDIM + i, isf32);
  }
  __syncthreads();
  for (int v = tid; v < EPB * HID; v += 256) {
    int le = v >> 5, h = v & 31;
    float acc = b1s[h];
    #pragma unroll
    for (int i = 0; i < FDIM; i++) acc += efs[le * FDIM + i] * w1s[i * HID + h];
    hs[le * 33 + h] = fmaxf(acc, 0.0f);
  }
  __syncthreads();
  #pragma unroll
  for (int q = 0; q < 4; q++) {
    int item = q * 256 + tid;
    int le = item >> 4, o = item & 15;
    int s = ssrc[le], d = sdst[le];
    const ushort_t* rrow = Rt + (size_t)s * RT_ROW;
    const u16x8* rr = (const u16x8*)(rrow + o * 32);
    float acc = bf2f(rrow[512 + o]);
    #pragma unroll
    for (int c = 0; c < 4; c++) {
      u16x8 rv = rr[c];
      #pragma unroll
      for (int j = 0; j < 8; j++) acc += hs[le * 33 + c * 8 + j] * bf2f(rv[j]);
    }
    atomicAdd(&agg[d * NC + o], acc);
  }
}

// GRU weight staging, transposed stride-17 (conflict-free reads wT[k*17+o])
__device__ __forceinline__ void stage_gru(const void* w_ih, const void* w_hh,
                                          const void* b_ih, const void* b_hh,
                                          float* wihT, float* whhT,
                                          float* bih, float* bhh, int isf32, int tid) {
  for (int kk = tid; kk < 3 * NC * NC; kk += 256) {
    int g = kk >> 8, rem = kk & 255, o = rem >> 4, k = rem & 15;
    wihT[g * 272 + k * 17 + o] = loadf(w_ih, kk, isf32);
    whhT[g * 272 + k * 17 + o] = loadf(w_hh, kk, isf32);
  }
  if (tid < 3 * NC) { bih[tid] = loadf(b_ih, tid, isf32); bhh[tid] = loadf(b_hh, tid, isf32); }
}

__device__ __forceinline__ float gru_core(const float* wihT, const float* whhT,
                                          const float* bih, const float* bhh,
                                          const float* x, const float* h, int o) {
  float gir = bih[o], giz = bih[NC + o], gin = bih[2 * NC + o];
  float ghr = bhh[o], ghz = bhh[NC + o], ghn = bhh[2 * NC + o];
  #pragma unroll
  for (int k = 0; k < NC; k++) {
    gir += x[k] * wihT[k * 17 + o];
    giz += x[k] * wihT[272 + k * 17 + o];
    gin += x[k] * wihT[544 + k * 17 + o];
    ghr += h[k] * whhT[k * 17 + o];
    ghz += h[k] * whhT[272 + k * 17 + o];
    ghn += h[k] * whhT[544 + k * 17 + o];
  }
  float r = sigmoidf_(gir + ghr);
  float z = sigmoidf_(giz + ghz);
  float n = tanhf_(gin + r * ghn);
  return (1.0f - z) * n + z * h[o];
}

// ---- fused GRU + Rt rebuild + agg re-zero ----
__global__ void k_update(const float* __restrict__ agg_in, const float* __restrict__ deg,
                         float* __restrict__ hx, const void* __restrict__ w_ih,
                         const void* __restrict__ w_hh, const void* __restrict__ b_ih,
                         const void* __restrict__ b_hh, const void* __restrict__ w2,
                         const void* __restrict__ b2, ushort_t* __restrict__ Rt,
                         float* __restrict__ agg_out, const int* __restrict__ flag) {
  __shared__ float w2t[256 * 36];
  __shared__ float b2s[256];
  __shared__ float wihT[3 * 272], whhT[3 * 272], bih[3 * NC], bhh[3 * NC];
  __shared__ float hx_l[16 * 17];
  int isf32 = flag[0];
  int tid = threadIdx.x;
  for (int k = tid; k < 256 * HID; k += 256) {
    int h = k >> 8, io = k & 255;
    w2t[io * 36 + h] = loadf(w2, h * 256 + io, isf32);
  }
  b2s[tid] = loadf(b2, tid, isf32);
  stage_gru(w_ih, w_hh, b_ih, b_hh, wihT, whhT, bih, bhh, isf32, tid);
  __syncthreads();

  int idx = blockIdx.x * 256 + tid;
  int v = idx >> 4, o = idx & 15, vl = tid >> 4;
  float inv = 1.0f / fmaxf(deg[v], 1.0f);
  float x[16], h[16];
  const float4* ar = (const float4*)(agg_in + v * NC);
  const float4* hr = (const float4*)(hx + v * NC);
  #pragma unroll
  for (int q = 0; q < 4; q++) {
    float4 a = ar[q], b = hr[q];
    x[4 * q + 0] = a.x * inv; x[4 * q + 1] = a.y * inv; x[4 * q + 2] = a.z * inv; x[4 * q + 3] = a.w * inv;
    h[4 * q + 0] = b.x; h[4 * q + 1] = b.y; h[4 * q + 2] = b.z; h[4 * q + 3] = b.w;
  }
  float hn = gru_core(wihT, whhT, bih, bhh, x, h, o);
  hx_l[vl * 17 + o] = hn;
  __syncthreads();
  hx[idx] = hn;
  agg_out[idx] = 0.0f;

  float hxr[16];
  #pragma unroll
  for (int i = 0; i < 16; i++) hxr[i] = hx_l[vl * 17 + i];
  ushort_t* rowp = Rt + (size_t)v * RT_ROW;
  #pragma unroll
  for (int c = 0; c < 4; c++) {
    float a[8] = {0, 0, 0, 0, 0, 0, 0, 0};
    #pragma unroll
    for (int i = 0; i < 16; i++) {
      const float* wp = &w2t[(i * 16 + o) * 36 + c * 8];
      float4 wa = *(const float4*)(wp);
      float4 wb = *(const float4*)(wp + 4);
      a[0] += hxr[i] * wa.x; a[1] += hxr[i] * wa.y; a[2] += hxr[i] * wa.z; a[3] += hxr[i] * wa.w;
      a[4] += hxr[i] * wb.x; a[5] += hxr[i] * wb.y; a[6] += hxr[i] * wb.z; a[7] += hxr[i] * wb.w;
    }
    u16x8 ov;
    #pragma unroll
    for (int j = 0; j < 8; j++) ov[j] = f2bf(a[j]);
    *(u16x8*)(rowp + o * 32 + c * 8) = ov;
  }
  float vb = 0.0f;
  #pragma unroll
  for (int i = 0; i < 16; i++) vb += hxr[i] * b2s[i * 16 + o];
  rowp[512 + o] = f2bf(vb);
}

// ---- final GRU: writes d_out ----
__global__ void k_gru(const float* __restrict__ agg, const float* __restrict__ deg,
                      const float* __restrict__ hx, const void* __restrict__ w_ih,
                      const void* __restrict__ w_hh, const void* __restrict__ b_ih,
                      const void* __restrict__ b_hh, void* __restrict__ out,
                      const int* __restrict__ flag) {
  __shared__ float wihT[3 * 272], whhT[3 * 272], bih[3 * NC], bhh[3 * NC];
  int isf32 = flag[0];
  int tid = threadIdx.x;
  stage_gru(w_ih, w_hh, b_ih, b_hh, wihT, whhT, bih, bhh, isf32, tid);
  __syncthreads();
  int idx = blockIdx.x * 256 + tid;
  int v = idx >> 4, o = idx & 15;
  float inv = 1.0f / fmaxf(deg[v], 1.0f);
  float x[16], h[16];
  const float4* ar = (const float4*)(agg + v * NC);
  const float4* hr = (const float4*)(hx + v * NC);
  #pragma unroll
  for (int q = 0; q < 4; q++) {
    float4 a = ar[q], b = hr[q];
    x[4 * q + 0] = a.x * inv; x[4 * q + 1] = a.y * inv; x[4 * q + 2] = a.z * inv; x[4 * q + 3] = a.w * inv;
    h[4 * q + 0] = b.x; h[4 * q + 1] = b.y; h[4 * q + 2] = b.z; h[4 * q + 3] = b.w;
  }
  float hn = gru_core(wihT, whhT, bih, bhh, x, h, o);
  if (isf32) ((float*)out)[idx] = hn;
  else       ((ushort_t*)out)[idx] = f2bf(hn);
}

extern "C" void kernel_launch(void* const* d_in, const int* in_sizes, int n_in,
                              void* d_out, int out_size, void* d_ws, size_t ws_size,
                              hipStream_t stream) {
  const void* hx_in = d_in[0];
  const void* ef    = d_in[1];
  const int*  esrc  = (const int*)d_in[2];
  const int*  edst  = (const int*)d_in[3];
  const void* w1    = d_in[4];
  const void* b1    = d_in[5];
  const void* w2    = d_in[6];
  const void* b2    = d_in[7];
  const void* wih   = d_in[8];
  const void* whh   = d_in[9];
  const void* bih_g = d_in[10];
  const void* bhh_g = d_in[11];

  char* ws = (char*)d_ws;
  float* hx32 = (float*)(ws + 0);           //  3,200,000
  float* agg  = (float*)(ws + 3200000);     //  3,200,000
  int*   flag = (int*)  (ws + 6400000);     //        256
  float* deg  = (float*)(ws + 6400256);     //    200,000
  int*   hist = (int*)  (ws + 6600256);     //     25,600  (deg+hist = zero region)

  // mode 2: sorted + precomputed hidden (113.8 MB); mode 1: sorted, MLP in msg
  // (65.8 MB, R5-proven); mode 0: unsorted fallback.
  int mode = (ws_size >= (size_t)113825856) ? 2 : (ws_size >= (size_t)65825856) ? 1 : 0;
  uint_t* srcdst = 0; uint2* sortbuf = 0; ushort_t* hidden = 0; ushort_t* Rt;
  if (mode == 2) {
    srcdst = (uint_t*)(ws + 6625856);        //  3,200,000
    Rt     = (ushort_t*)(ws + 9825856);      // 52,800,000
    hidden = (ushort_t*)(ws + 62625856);     // 51,200,000 -> ends 113,825,856
  } else if (mode == 1) {
    sortbuf = (uint2*)(ws + 6625856);        //  6,400,000
    Rt      = (ushort_t*)(ws + 13025856);    // 52,800,000 -> ends 65,825,856
  } else {
    sortbuf = (uint2*)(ws + 6625856);        // unused
    Rt      = (ushort_t*)(ws + 6625856);     // -> ends 59,425,856
  }
  int sorted = (mode >= 1);

  k_init<<<(ZWORDS + 255) / 256, 256, 0, stream>>>((const unsigned int*)hx_in, flag, (int*)deg);
  k_pre<<<N_EDGES / 256, 256, 0, stream>>>(hx_in, hx32, esrc, edst, deg, hist, flag);
  k_scan_rnode<<<(N_NODES * NC) / 256 + 1, 256, 0, stream>>>(hist, hx32, w2, b2, Rt, agg,
                                                             flag, sorted);
  if (mode == 2) {
    k_scatter_mlp<<<N_EDGES / 256, 256, 0, stream>>>(esrc, edst, hist, srcdst, hidden,
                                                     ef, w1, b1, flag);
    k_msg2<<<N_EDGES / EPB, 256, 0, stream>>>(srcdst, hidden, Rt, agg);
    k_update<<<(N_NODES * NC) / 256, 256, 0, stream>>>(agg, deg, hx32, wih, whh, bih_g, bhh_g,
                                                       w2, b2, Rt, agg, flag);
    k_msg2<<<N_EDGES / EPB, 256, 0, stream>>>(srcdst, hidden, Rt, agg);
  } else {
    if (mode == 1)
      k_scatter1<<<N_EDGES / 256, 256, 0, stream>>>(esrc, edst, hist, sortbuf);
    k_msg<<<N_EDGES / EPB, 256, 0, stream>>>(esrc, edst, sortbuf, ef, w1, b1, Rt, agg, flag, sorted);
    k_update<<<(N_NODES * NC) / 256, 256, 0, stream>>>(agg, deg, hx32, wih, whh, bih_g, bhh_g,
                                                       w2, b2, Rt, agg, flag);
    k_msg<<<N_EDGES / EPB, 256, 0, stream>>>(esrc, edst, sortbuf, ef, w1, b1, Rt, agg, flag, sorted);
  }
  k_gru<<<(N_NODES * NC) / 256, 256, 0, stream>>>(agg, deg, hx32, wih, whh, bih_g, bhh_g,
                                                  d_out, flag);
}